// Round 10
// baseline (241.043 us; speedup 1.0000x reference)
//
#include <hip/hip_runtime.h>
#include <hip/hip_bf16.h>

#define NROWS 50000
#define MOBS  2048
#define EDIM  512
#define ODIM  256
#define BM2   128
#define NT2   391               // ceil(50000/128)

typedef short s16x8 __attribute__((ext_vector_type(8)));
typedef float f32x4 __attribute__((ext_vector_type(4)));

typedef const __attribute__((address_space(1))) unsigned int* gptr_t;
typedef __attribute__((address_space(3))) unsigned int* lptr_t;

__device__ __forceinline__ unsigned short f32_to_bf16(float f) {
    unsigned int u = __float_as_uint(f);
    u += 0x7fffu + ((u >> 16) & 1u);     // RNE
    return (unsigned short)(u >> 16);
}

__device__ __forceinline__ s16x8 pack8(f32x4 a, f32x4 b) {
    unsigned int p0, p1, p2, p3;
    asm("v_cvt_pk_bf16_f32 %0, %1, %2" : "=v"(p0) : "v"(a[0]), "v"(a[1]));
    asm("v_cvt_pk_bf16_f32 %0, %1, %2" : "=v"(p1) : "v"(a[2]), "v"(a[3]));
    asm("v_cvt_pk_bf16_f32 %0, %1, %2" : "=v"(p2) : "v"(b[0]), "v"(b[1]));
    asm("v_cvt_pk_bf16_f32 %0, %1, %2" : "=v"(p3) : "v"(b[2]), "v"(b[3]));
    union { unsigned int u[4]; s16x8 v; } r;
    r.u[0] = p0; r.u[1] = p1; r.u[2] = p2; r.u[3] = p3;
    return r.v;
}

// Device-scope grid barrier; counters are memset to 0 before each launch.
__device__ __forceinline__ void gridbar(unsigned int* c, unsigned int nb) {
    __syncthreads();
    if (threadIdx.x == 0) {
        __hip_atomic_fetch_add(c, 1u, __ATOMIC_ACQ_REL, __HIP_MEMORY_SCOPE_AGENT);
        while (__hip_atomic_load(c, __ATOMIC_ACQUIRE, __HIP_MEMORY_SCOPE_AGENT) < nb)
            __builtin_amdgcn_s_sleep(8);
    }
    __syncthreads();
}

// ---------------------------------------------------------------------------
// Fused chain: one dispatch, 384 blocks x 256 thr (all co-resident).
//  P0: zero G,P        -> bar0
//  P1: G = obs^T obs (b<256, split-K 16, atomic) ; P = Wq^T Wk (b>=256,
//      split-K 4, atomic)                         -> bar1
//  P2: PG = P @ G  [512,256] K=256 (b<32)         -> bar2
//  P3: Uf = frag_kkmajor(PG @ Wv^T + I) (b<64)
// ---------------------------------------------------------------------------
__global__ __launch_bounds__(256) void chain_fused(
    const float* __restrict__ obs, const float* __restrict__ Wq,
    const float* __restrict__ Wk, const float* __restrict__ Wv,
    float* __restrict__ G, float* __restrict__ P, float* __restrict__ PG,
    unsigned short* __restrict__ Uf, unsigned int* __restrict__ bar) {
    __shared__ float SA[16][68];
    __shared__ float SB[16][68];
    const int b = blockIdx.x;
    const int t = threadIdx.x;
    const int tx = t & 15, ty = t >> 4;

    // ---- P0: zero G (65536) + P (131072), contiguous ----
    {
        size_t base = (size_t)b * 256 + t;
        G[base] = 0.f;                 // covers G and P's first half
        G[base + 98304] = 0.f;         // covers rest (G,P contiguous in ws)
    }
    gridbar(bar + 0, 384);

    // ---- P1 ----
    {
        const float *A, *B;
        float* C;
        int lda, ldb, k_lo, k_hi, bx, by;
        if (b < 256) {
            bx = b & 3; by = (b >> 2) & 3; int bz = b >> 4;
            A = obs; B = obs; C = G; lda = ODIM; ldb = ODIM;
            k_lo = bz * (MOBS / 16); k_hi = k_lo + MOBS / 16;
        } else {
            int i = b - 256;
            bx = i & 3; by = (i >> 2) & 7; int bz = i >> 5;
            A = Wq; B = Wk; C = P; lda = EDIM; ldb = ODIM;
            k_lo = bz * (EDIM / 4); k_hi = k_lo + EDIM / 4;
        }
        const int i0 = by * 64, j0 = bx * 64;
        float acc[4][4];
#pragma unroll
        for (int a = 0; a < 4; ++a)
#pragma unroll
            for (int c2 = 0; c2 < 4; ++c2) acc[a][c2] = 0.f;
        for (int k0 = k_lo; k0 < k_hi; k0 += 16) {
#pragma unroll
            for (int r = 0; r < 4; ++r) {
                int idx = t + 256 * r;
                int mm = idx & 63, kk2 = idx >> 6;
                SA[kk2][mm] = A[(size_t)(k0 + kk2) * lda + i0 + mm];
            }
#pragma unroll
            for (int r = 0; r < 4; ++r) {
                int idx = t + 256 * r;
                int jj = idx & 63, kk2 = idx >> 6;
                SB[kk2][jj] = B[(size_t)(k0 + kk2) * ldb + j0 + jj];
            }
            __syncthreads();
#pragma unroll
            for (int kk2 = 0; kk2 < 16; ++kk2) {
                float4 a4 = *(const float4*)&SA[kk2][ty * 4];
                float4 b4 = *(const float4*)&SB[kk2][tx * 4];
                float av[4] = {a4.x, a4.y, a4.z, a4.w};
                float bv[4] = {b4.x, b4.y, b4.z, b4.w};
#pragma unroll
                for (int a = 0; a < 4; ++a)
#pragma unroll
                    for (int c2 = 0; c2 < 4; ++c2) acc[a][c2] += av[a] * bv[c2];
            }
            __syncthreads();
        }
#pragma unroll
        for (int a = 0; a < 4; ++a)
#pragma unroll
            for (int c2 = 0; c2 < 4; ++c2)
                atomicAdd(&C[(size_t)(i0 + ty * 4 + a) * ODIM + j0 + tx * 4 + c2],
                          acc[a][c2]);
    }
    gridbar(bar + 1, 384);

    // ---- P2: PG = P @ G  (b < 32) ----
    if (b < 32) {
        const int i0 = (b >> 2) * 64, j0 = (b & 3) * 64;
        float acc[4][4];
#pragma unroll
        for (int a = 0; a < 4; ++a)
#pragma unroll
            for (int c2 = 0; c2 < 4; ++c2) acc[a][c2] = 0.f;
        for (int k0 = 0; k0 < ODIM; k0 += 16) {
#pragma unroll
            for (int r = 0; r < 4; ++r) {
                int idx = t + 256 * r;
                int kk2 = idx & 15, mm = idx >> 4;
                SA[kk2][mm] = P[(size_t)(i0 + mm) * ODIM + k0 + kk2];
            }
#pragma unroll
            for (int r = 0; r < 4; ++r) {
                int idx = t + 256 * r;
                int jj = idx & 63, kk2 = idx >> 6;
                SB[kk2][jj] = G[(size_t)(k0 + kk2) * ODIM + j0 + jj];
            }
            __syncthreads();
#pragma unroll
            for (int kk2 = 0; kk2 < 16; ++kk2) {
                float4 a4 = *(const float4*)&SA[kk2][ty * 4];
                float4 b4 = *(const float4*)&SB[kk2][tx * 4];
                float av[4] = {a4.x, a4.y, a4.z, a4.w};
                float bv[4] = {b4.x, b4.y, b4.z, b4.w};
#pragma unroll
                for (int a = 0; a < 4; ++a)
#pragma unroll
                    for (int c2 = 0; c2 < 4; ++c2) acc[a][c2] += av[a] * bv[c2];
            }
            __syncthreads();
        }
#pragma unroll
        for (int a = 0; a < 4; ++a) {
            float4 o = make_float4(acc[a][0], acc[a][1], acc[a][2], acc[a][3]);
            *(float4*)&PG[(size_t)(i0 + ty * 4 + a) * ODIM + j0 + tx * 4] = o;
        }
    }
    gridbar(bar + 2, 384);

    // ---- P3: Uf = frag(PG @ Wv^T + I)  (b < 64), kk-major frag layout ----
    if (b < 64) {
        const int i0 = (b >> 3) * 64, j0 = (b & 7) * 64;
        float acc[4][4];
#pragma unroll
        for (int a = 0; a < 4; ++a)
#pragma unroll
            for (int c2 = 0; c2 < 4; ++c2) acc[a][c2] = 0.f;
        for (int k0 = 0; k0 < ODIM; k0 += 16) {
#pragma unroll
            for (int r = 0; r < 4; ++r) {
                int idx = t + 256 * r;
                int kk2 = idx & 15, mm = idx >> 4;
                SA[kk2][mm] = PG[(size_t)(i0 + mm) * ODIM + k0 + kk2];
            }
#pragma unroll
            for (int r = 0; r < 4; ++r) {
                int idx = t + 256 * r;
                int kk2 = idx & 15, jj = idx >> 4;
                SB[kk2][jj] = Wv[(size_t)(j0 + jj) * ODIM + k0 + kk2];
            }
            __syncthreads();
#pragma unroll
            for (int kk2 = 0; kk2 < 16; ++kk2) {
                float4 a4 = *(const float4*)&SA[kk2][ty * 4];
                float4 b4 = *(const float4*)&SB[kk2][tx * 4];
                float av[4] = {a4.x, a4.y, a4.z, a4.w};
                float bv[4] = {b4.x, b4.y, b4.z, b4.w};
#pragma unroll
                for (int a = 0; a < 4; ++a)
#pragma unroll
                    for (int c2 = 0; c2 < 4; ++c2) acc[a][c2] += av[a] * bv[c2];
            }
            __syncthreads();
        }
#pragma unroll
        for (int a = 0; a < 4; ++a)
#pragma unroll
            for (int c2 = 0; c2 < 4; ++c2) {
                int i = i0 + ty * 4 + a;       // k-dim of main GEMM
                int j = j0 + tx * 4 + c2;      // col of main GEMM
                float v = acc[a][c2] + (i == j ? 1.f : 0.f);
                size_t idx = ((size_t)(((i >> 5) * 32 + (j >> 4)) * 64
                               + ((i >> 3) & 3) * 16 + (j & 15))) * 8 + (i & 7);
                Uf[idx] = f32_to_bf16(v);
            }
    }
}

// ---------------------------------------------------------------------------
// Main: out = LayerNorm(node @ (U+I)).  3-deep DMA pipeline, counted vmcnt.
// Tile 128x512, BK=32, 16 K-steps. LDS: A 3x16KB + B 3x32KB = 144KB.
// Per iter: issue dma(kt+2) -> s_waitcnt vmcnt(12) (buf kt landed, all waves
// after barrier) -> s_barrier -> compute(kt) -> s_barrier (reads done before
// buf reuse). Never drains vmcnt to 0 in the main loop (T4).
// ---------------------------------------------------------------------------
__global__ __launch_bounds__(512, 2) void gemm_pipe_ln(
    const float* __restrict__ node, const unsigned short* __restrict__ Uf,
    const float* __restrict__ gamma, const float* __restrict__ beta,
    float* __restrict__ out) {
    __shared__ char smem[147456];           // A: [3][16KB] | B: [3][32KB]
    char* Areg = smem;
    char* Breg = smem + 49152;
    float* lds_s  = (float*)smem;           // stats alias (A dead after loop)
    float* lds_q  = (float*)smem + 512;
    float* lds_mu = (float*)smem + 1024;
    float* lds_rs = (float*)smem + 1152;

    const int t  = threadIdx.x;
    const int w  = t >> 6, l = t & 63;
    const int rg = w >> 2, cg = w & 3;
    const int lr = l & 15, lk = l >> 4;
    const int m0 = blockIdx.x * BM2;

    // DMA source: lane covers (row = w*8 + (l>>3), chunk = l&7), source
    // chunk pre-swizzled (linear LDS dest + inv-swz source, rule #21).
    const int sr = w * 8 + (l >> 3);
    const int schunk = (l & 7) ^ ((l >> 3) & 7);
    int gr0 = m0 + sr;      if (gr0 > NROWS - 1) gr0 = NROWS - 1;
    int gr1 = m0 + sr + 64; if (gr1 > NROWS - 1) gr1 = NROWS - 1;
    const char* asrc0 = (const char*)node + (size_t)gr0 * 2048 + schunk * 16;
    const char* asrc1 = (const char*)node + (size_t)gr1 * 2048 + schunk * 16;
    const char* bsrc  = (const char*)Uf + (size_t)w * 4096 + (size_t)l * 16;

    auto dma = [&](int buf, int kt) {
        char* ad = Areg + buf * 16384 + w * 1024;
        __builtin_amdgcn_global_load_lds((gptr_t)(asrc0 + kt * 128),
                                         (lptr_t)ad, 16, 0, 0);
        __builtin_amdgcn_global_load_lds((gptr_t)(asrc1 + kt * 128),
                                         (lptr_t)(ad + 8192), 16, 0, 0);
        char* bd = Breg + buf * 32768 + w * 4096;
        const char* bs = bsrc + (size_t)kt * 32768;
#pragma unroll
        for (int j = 0; j < 4; ++j)
            __builtin_amdgcn_global_load_lds((gptr_t)(bs + j * 1024),
                                             (lptr_t)(bd + j * 1024), 16, 0, 0);
    };

    f32x4 acc[4][8];
#pragma unroll
    for (int mi = 0; mi < 4; ++mi)
#pragma unroll
        for (int ni = 0; ni < 8; ++ni)
            acc[mi][ni] = (f32x4){0.f, 0.f, 0.f, 0.f};

    auto compute = [&](int cur) {
        const char* bbase = Breg + cur * 32768 + cg * 8192 + l * 16;
        s16x8 bfr[8];
#pragma unroll
        for (int ni = 0; ni < 8; ++ni)
            bfr[ni] = *(const s16x8*)(bbase + ni * 1024);
        s16x8 afr[4];
#pragma unroll
        for (int mi = 0; mi < 4; ++mi) {
            int row = rg * 64 + mi * 16 + lr;          // row&7 == lr&7
            const char* rb = Areg + cur * 16384 + row * 128;
            f32x4 a0 = *(const f32x4*)(rb + ((2 * lk)     ^ (lr & 7)) * 16);
            f32x4 a1 = *(const f32x4*)(rb + ((2 * lk + 1) ^ (lr & 7)) * 16);
            afr[mi] = pack8(a0, a1);
        }
#pragma unroll
        for (int mi = 0; mi < 4; ++mi)
#pragma unroll
            for (int ni = 0; ni < 8; ++ni)
                acc[mi][ni] = __builtin_amdgcn_mfma_f32_16x16x32_bf16(
                    afr[mi], bfr[ni], acc[mi][ni], 0, 0, 0);
    };

    dma(0, 0);
    dma(1, 1);

#pragma unroll 1
    for (int kt = 0; kt < 14; ++kt) {
        dma((kt + 2) % 3, kt + 2);
        asm volatile("s_waitcnt vmcnt(12)" ::: "memory");
        __builtin_amdgcn_sched_barrier(0);
        __builtin_amdgcn_s_barrier();
        compute(kt % 3);
        __builtin_amdgcn_s_barrier();
    }
    // kt = 14
    asm volatile("s_waitcnt vmcnt(6)" ::: "memory");
    __builtin_amdgcn_sched_barrier(0);
    __builtin_amdgcn_s_barrier();
    compute(14 % 3);
    __builtin_amdgcn_s_barrier();
    // kt = 15
    asm volatile("s_waitcnt vmcnt(0)" ::: "memory");
    __builtin_amdgcn_sched_barrier(0);
    __builtin_amdgcn_s_barrier();
    compute(15 % 3);
    __syncthreads();                   // all reads done before stats aliasing

    // ---- LN stats ----
#pragma unroll
    for (int mi = 0; mi < 4; ++mi) {
#pragma unroll
        for (int j = 0; j < 4; ++j) {
            float sm = 0.f, q = 0.f;
#pragma unroll
            for (int ni = 0; ni < 8; ++ni) {
                float v = acc[mi][ni][j];
                sm += v; q += v * v;
            }
#pragma unroll
            for (int off = 1; off < 16; off <<= 1) {
                sm += __shfl_xor(sm, off);
                q  += __shfl_xor(q, off);
            }
            if (lr == 0) {
                int row = rg * 64 + mi * 16 + lk * 4 + j;
                lds_s[cg * 128 + row] = sm;
                lds_q[cg * 128 + row] = q;
            }
        }
    }
    __syncthreads();
    if (t < 128) {
        float sm = lds_s[t] + lds_s[128 + t] + lds_s[256 + t] + lds_s[384 + t];
        float q  = lds_q[t] + lds_q[128 + t] + lds_q[256 + t] + lds_q[384 + t];
        float mu  = sm * (1.f / (float)EDIM);
        float var = q * (1.f / (float)EDIM) - mu * mu;
        lds_mu[t] = mu;
        lds_rs[t] = rsqrtf(var + 1e-6f);
    }
    __syncthreads();

    float gv[8], bv[8];
#pragma unroll
    for (int ni = 0; ni < 8; ++ni) {
        int col = cg * 128 + ni * 16 + lr;
        gv[ni] = gamma[col];
        bv[ni] = beta[col];
    }

#pragma unroll
    for (int mi = 0; mi < 4; ++mi) {
#pragma unroll
        for (int j = 0; j < 4; ++j) {
            int row = rg * 64 + mi * 16 + lk * 4 + j;
            int gr = m0 + row;
            if (gr < NROWS) {
                float mu = lds_mu[row], rs = lds_rs[row];
                float* op = out + (size_t)gr * EDIM + cg * 128 + lr;
#pragma unroll
                for (int ni = 0; ni < 8; ++ni)
                    op[ni * 16] = (acc[mi][ni][j] - mu) * rs * gv[ni] + bv[ni];
            }
        }
    }
}

// ---------------------------------------------------------------------------
extern "C" void kernel_launch(void* const* d_in, const int* in_sizes, int n_in,
                              void* d_out, int out_size, void* d_ws, size_t ws_size,
                              hipStream_t stream) {
    const float* node  = (const float*)d_in[0];   // [N, E]
    const float* obs   = (const float*)d_in[1];   // [M, O]
    const float* Wq    = (const float*)d_in[2];   // [E, E]
    const float* Wk    = (const float*)d_in[3];   // [E, O]
    const float* Wv    = (const float*)d_in[4];   // [E, O]
    const float* gamma = (const float*)d_in[5];   // [E]
    const float* beta  = (const float*)d_in[6];   // [E]
    float* out = (float*)d_out;

    float* ws = (float*)d_ws;
    float*          G  = ws;                        // [256,256] f32
    float*          P  = G  + ODIM * ODIM;          // [512,256] f32 (contiguous after G)
    float*          PG = P  + EDIM * ODIM;          // [512,256] f32
    unsigned short* Uf = (unsigned short*)(PG + EDIM * ODIM); // kk-major frag bf16
    unsigned int*   bar = (unsigned int*)((char*)d_ws + (8u << 20)); // 8MB offset

    hipMemsetAsync((void*)bar, 0, 64, stream);
    // Chain: memset+G+P+PG+Uf in ONE dispatch with device grid-barriers
    chain_fused<<<dim3(384), 256, 0, stream>>>(obs, Wq, Wk, Wv, G, P, PG, Uf, bar);
    // Main: out = LN(node @ (U+I)), 3-deep counted-vmcnt pipeline
    gemm_pipe_ln<<<dim3(NT2), 512, 0, stream>>>(node, Uf, gamma, beta, out);
}

// Round 11
// 125.034 us; speedup vs baseline: 1.9278x; 1.9278x over previous
//
#include <hip/hip_runtime.h>
#include <hip/hip_bf16.h>

#define NROWS 50000
#define MOBS  2048
#define EDIM  512
#define ODIM  256
#define BM2   128
#define NT2   391               // ceil(50000/128)

typedef short s16x8 __attribute__((ext_vector_type(8)));
typedef float f32x4 __attribute__((ext_vector_type(4)));

typedef const __attribute__((address_space(1))) unsigned int* gptr_t;
typedef __attribute__((address_space(3))) unsigned int* lptr_t;

__device__ __forceinline__ unsigned short f32_to_bf16(float f) {
    unsigned int u = __float_as_uint(f);
    u += 0x7fffu + ((u >> 16) & 1u);     // RNE
    return (unsigned short)(u >> 16);
}

__device__ __forceinline__ s16x8 pack8(f32x4 a, f32x4 b) {
    unsigned int p0, p1, p2, p3;
    asm("v_cvt_pk_bf16_f32 %0, %1, %2" : "=v"(p0) : "v"(a[0]), "v"(a[1]));
    asm("v_cvt_pk_bf16_f32 %0, %1, %2" : "=v"(p1) : "v"(a[2]), "v"(a[3]));
    asm("v_cvt_pk_bf16_f32 %0, %1, %2" : "=v"(p2) : "v"(b[0]), "v"(b[1]));
    asm("v_cvt_pk_bf16_f32 %0, %1, %2" : "=v"(p3) : "v"(b[2]), "v"(b[3]));
    union { unsigned int u[4]; s16x8 v; } r;
    r.u[0] = p0; r.u[1] = p1; r.u[2] = p2; r.u[3] = p3;
    return r.v;
}

// ---------------------------------------------------------------------------
// D1: G = obs^T obs (b<256, split-K 16) and P = Wq^T Wk (b>=256, split-K 4).
// 64x64 tiles, atomicAdd into pre-zeroed C.  (R9 verbatim)
// ---------------------------------------------------------------------------
__global__ __launch_bounds__(256) void gp_fused(const float* __restrict__ obs,
                                                const float* __restrict__ Wq,
                                                const float* __restrict__ Wk,
                                                float* __restrict__ G,
                                                float* __restrict__ P) {
    __shared__ float SA[16][68];
    __shared__ float SB[16][68];
    const int b = blockIdx.x;
    const float *A, *B;
    float* C;
    int lda, ldb, k_lo, k_hi, bx, by;
    if (b < 256) {
        bx = b & 3; by = (b >> 2) & 3; int bz = b >> 4;
        A = obs; B = obs; C = G; lda = ODIM; ldb = ODIM;
        k_lo = bz * (MOBS / 16); k_hi = k_lo + MOBS / 16;
    } else {
        int i = b - 256;
        bx = i & 3; by = (i >> 2) & 7; int bz = i >> 5;
        A = Wq; B = Wk; C = P; lda = EDIM; ldb = ODIM;
        k_lo = bz * (EDIM / 4); k_hi = k_lo + EDIM / 4;
    }
    const int t  = threadIdx.x;
    const int tx = t & 15, ty = t >> 4;
    const int i0 = by * 64, j0 = bx * 64;

    float acc[4][4];
#pragma unroll
    for (int a = 0; a < 4; ++a)
#pragma unroll
        for (int c2 = 0; c2 < 4; ++c2) acc[a][c2] = 0.f;

    for (int k0 = k_lo; k0 < k_hi; k0 += 16) {
#pragma unroll
        for (int r = 0; r < 4; ++r) {
            int idx = t + 256 * r;
            int mm = idx & 63, kk2 = idx >> 6;
            SA[kk2][mm] = A[(size_t)(k0 + kk2) * lda + i0 + mm];
        }
#pragma unroll
        for (int r = 0; r < 4; ++r) {
            int idx = t + 256 * r;
            int jj = idx & 63, kk2 = idx >> 6;
            SB[kk2][jj] = B[(size_t)(k0 + kk2) * ldb + j0 + jj];
        }
        __syncthreads();
#pragma unroll
        for (int kk2 = 0; kk2 < 16; ++kk2) {
            float4 a4 = *(const float4*)&SA[kk2][ty * 4];
            float4 b4 = *(const float4*)&SB[kk2][tx * 4];
            float av[4] = {a4.x, a4.y, a4.z, a4.w};
            float bv[4] = {b4.x, b4.y, b4.z, b4.w};
#pragma unroll
            for (int a = 0; a < 4; ++a)
#pragma unroll
                for (int c2 = 0; c2 < 4; ++c2) acc[a][c2] += av[a] * bv[c2];
        }
        __syncthreads();
    }
#pragma unroll
    for (int a = 0; a < 4; ++a)
#pragma unroll
        for (int c2 = 0; c2 < 4; ++c2)
            atomicAdd(&C[(size_t)(i0 + ty * 4 + a) * ODIM + j0 + tx * 4 + c2],
                      acc[a][c2]);
}

// ---------------------------------------------------------------------------
// Small-chain GEMM (R9 verbatim): 64x64 tile, 4x4 micro-tile, split-K,
// optional kk-major frag-bf16 output (+I residual fold).
// FRAG layout: granule (kk,f) contiguous 1KB at (kk*32+f)*1024 bytes, so a
// K-step's whole B-tile (32 frag-cols) is one contiguous 32KB chunk for DMA.
// ---------------------------------------------------------------------------
template <int TA, int TB, int SPLIT, int FRAG>
__global__ __launch_bounds__(256) void sgemm4(const float* __restrict__ A,
                                              const float* __restrict__ B,
                                              void* __restrict__ Cv,
                                              int NN, int KK, int lda, int ldb) {
    __shared__ float SA[16][68];
    __shared__ float SB[16][68];
    const int t  = threadIdx.x;
    const int tx = t & 15, ty = t >> 4;
    const int i0 = blockIdx.y * 64, j0 = blockIdx.x * 64;
    int k_lo = 0, k_hi = KK;
    if (SPLIT > 1) { int ch = KK / SPLIT; k_lo = blockIdx.z * ch; k_hi = k_lo + ch; }

    float acc[4][4];
#pragma unroll
    for (int a = 0; a < 4; ++a)
#pragma unroll
        for (int b = 0; b < 4; ++b) acc[a][b] = 0.f;

    for (int k0 = k_lo; k0 < k_hi; k0 += 16) {
#pragma unroll
        for (int r = 0; r < 4; ++r) {
            int idx = t + 256 * r;
            int mm, kk2;
            if (TA) { mm = idx & 63; kk2 = idx >> 6; }
            else    { kk2 = idx & 15; mm = idx >> 4; }
            SA[kk2][mm] = TA ? A[(size_t)(k0 + kk2) * lda + i0 + mm]
                             : A[(size_t)(i0 + mm) * lda + k0 + kk2];
        }
#pragma unroll
        for (int r = 0; r < 4; ++r) {
            int idx = t + 256 * r;
            int jj, kk2;
            if (TB) { kk2 = idx & 15; jj = idx >> 4; }
            else    { jj = idx & 63; kk2 = idx >> 6; }
            SB[kk2][jj] = TB ? B[(size_t)(j0 + jj) * ldb + k0 + kk2]
                             : B[(size_t)(k0 + kk2) * ldb + j0 + jj];
        }
        __syncthreads();
#pragma unroll
        for (int kk2 = 0; kk2 < 16; ++kk2) {
            float4 a4 = *(const float4*)&SA[kk2][ty * 4];
            float4 b4 = *(const float4*)&SB[kk2][tx * 4];
            float av[4] = {a4.x, a4.y, a4.z, a4.w};
            float bv[4] = {b4.x, b4.y, b4.z, b4.w};
#pragma unroll
            for (int a = 0; a < 4; ++a)
#pragma unroll
                for (int b = 0; b < 4; ++b) acc[a][b] += av[a] * bv[b];
        }
        __syncthreads();
    }

    if (FRAG) {
        unsigned short* C = (unsigned short*)Cv;
#pragma unroll
        for (int a = 0; a < 4; ++a)
#pragma unroll
            for (int b = 0; b < 4; ++b) {
                int i = i0 + ty * 4 + a;       // k-dim of main GEMM
                int j = j0 + tx * 4 + b;       // col of main GEMM
                float v = acc[a][b] + (i == j ? 1.f : 0.f);
                size_t idx = ((size_t)(((i >> 5) * 32 + (j >> 4)) * 64
                               + ((i >> 3) & 3) * 16 + (j & 15))) * 8 + (i & 7);
                C[idx] = f32_to_bf16(v);
            }
    } else if (SPLIT > 1) {
        float* C = (float*)Cv;
#pragma unroll
        for (int a = 0; a < 4; ++a)
#pragma unroll
            for (int b = 0; b < 4; ++b)
                atomicAdd(&C[(size_t)(i0 + ty * 4 + a) * NN + j0 + tx * 4 + b],
                          acc[a][b]);
    } else {
        float* C = (float*)Cv;
#pragma unroll
        for (int a = 0; a < 4; ++a) {
            float4 o = make_float4(acc[a][0], acc[a][1], acc[a][2], acc[a][3]);
            *(float4*)&C[(size_t)(i0 + ty * 4 + a) * NN + j0 + tx * 4] = o;
        }
    }
}

// ---------------------------------------------------------------------------
// Main: out = LayerNorm(node @ (U+I)).  (R10 verbatim)
// 3-deep DMA pipeline, counted vmcnt. Tile 128x512, BK=32, 16 K-steps.
// LDS: A 3x16KB + B 3x32KB = 144KB. Per iter: issue dma(kt+2) ->
// s_waitcnt vmcnt(12) -> s_barrier -> compute(kt) -> s_barrier.
// Never drains vmcnt to 0 in the main loop (T4).
// ---------------------------------------------------------------------------
__global__ __launch_bounds__(512, 2) void gemm_pipe_ln(
    const float* __restrict__ node, const unsigned short* __restrict__ Uf,
    const float* __restrict__ gamma, const float* __restrict__ beta,
    float* __restrict__ out) {
    __shared__ char smem[147456];           // A: [3][16KB] | B: [3][32KB]
    char* Areg = smem;
    char* Breg = smem + 49152;
    float* lds_s  = (float*)smem;           // stats alias (A dead after loop)
    float* lds_q  = (float*)smem + 512;
    float* lds_mu = (float*)smem + 1024;
    float* lds_rs = (float*)smem + 1152;

    const int t  = threadIdx.x;
    const int w  = t >> 6, l = t & 63;
    const int rg = w >> 2, cg = w & 3;
    const int lr = l & 15, lk = l >> 4;
    const int m0 = blockIdx.x * BM2;

    // DMA source: lane covers (row = w*8 + (l>>3), chunk = l&7), source
    // chunk pre-swizzled (linear LDS dest + inv-swz source, rule #21).
    const int sr = w * 8 + (l >> 3);
    const int schunk = (l & 7) ^ ((l >> 3) & 7);
    int gr0 = m0 + sr;      if (gr0 > NROWS - 1) gr0 = NROWS - 1;
    int gr1 = m0 + sr + 64; if (gr1 > NROWS - 1) gr1 = NROWS - 1;
    const char* asrc0 = (const char*)node + (size_t)gr0 * 2048 + schunk * 16;
    const char* asrc1 = (const char*)node + (size_t)gr1 * 2048 + schunk * 16;
    const char* bsrc  = (const char*)Uf + (size_t)w * 4096 + (size_t)l * 16;

    auto dma = [&](int buf, int kt) {
        char* ad = Areg + buf * 16384 + w * 1024;
        __builtin_amdgcn_global_load_lds((gptr_t)(asrc0 + kt * 128),
                                         (lptr_t)ad, 16, 0, 0);
        __builtin_amdgcn_global_load_lds((gptr_t)(asrc1 + kt * 128),
                                         (lptr_t)(ad + 8192), 16, 0, 0);
        char* bd = Breg + buf * 32768 + w * 4096;
        const char* bs = bsrc + (size_t)kt * 32768;
#pragma unroll
        for (int j = 0; j < 4; ++j)
            __builtin_amdgcn_global_load_lds((gptr_t)(bs + j * 1024),
                                             (lptr_t)(bd + j * 1024), 16, 0, 0);
    };

    f32x4 acc[4][8];
#pragma unroll
    for (int mi = 0; mi < 4; ++mi)
#pragma unroll
        for (int ni = 0; ni < 8; ++ni)
            acc[mi][ni] = (f32x4){0.f, 0.f, 0.f, 0.f};

    auto compute = [&](int cur) {
        const char* bbase = Breg + cur * 32768 + cg * 8192 + l * 16;
        s16x8 bfr[8];
#pragma unroll
        for (int ni = 0; ni < 8; ++ni)
            bfr[ni] = *(const s16x8*)(bbase + ni * 1024);
        s16x8 afr[4];
#pragma unroll
        for (int mi = 0; mi < 4; ++mi) {
            int row = rg * 64 + mi * 16 + lr;          // row&7 == lr&7
            const char* rb = Areg + cur * 16384 + row * 128;
            f32x4 a0 = *(const f32x4*)(rb + ((2 * lk)     ^ (lr & 7)) * 16);
            f32x4 a1 = *(const f32x4*)(rb + ((2 * lk + 1) ^ (lr & 7)) * 16);
            afr[mi] = pack8(a0, a1);
        }
#pragma unroll
        for (int mi = 0; mi < 4; ++mi)
#pragma unroll
            for (int ni = 0; ni < 8; ++ni)
                acc[mi][ni] = __builtin_amdgcn_mfma_f32_16x16x32_bf16(
                    afr[mi], bfr[ni], acc[mi][ni], 0, 0, 0);
    };

    dma(0, 0);
    dma(1, 1);

#pragma unroll 1
    for (int kt = 0; kt < 14; ++kt) {
        dma((kt + 2) % 3, kt + 2);
        asm volatile("s_waitcnt vmcnt(12)" ::: "memory");
        __builtin_amdgcn_sched_barrier(0);
        __builtin_amdgcn_s_barrier();
        compute(kt % 3);
        __builtin_amdgcn_s_barrier();
    }
    // kt = 14
    asm volatile("s_waitcnt vmcnt(6)" ::: "memory");
    __builtin_amdgcn_sched_barrier(0);
    __builtin_amdgcn_s_barrier();
    compute(14 % 3);
    __builtin_amdgcn_s_barrier();
    // kt = 15
    asm volatile("s_waitcnt vmcnt(0)" ::: "memory");
    __builtin_amdgcn_sched_barrier(0);
    __builtin_amdgcn_s_barrier();
    compute(15 % 3);
    __syncthreads();                   // all reads done before stats aliasing

    // ---- LN stats ----
#pragma unroll
    for (int mi = 0; mi < 4; ++mi) {
#pragma unroll
        for (int j = 0; j < 4; ++j) {
            float sm = 0.f, q = 0.f;
#pragma unroll
            for (int ni = 0; ni < 8; ++ni) {
                float v = acc[mi][ni][j];
                sm += v; q += v * v;
            }
#pragma unroll
            for (int off = 1; off < 16; off <<= 1) {
                sm += __shfl_xor(sm, off);
                q  += __shfl_xor(q, off);
            }
            if (lr == 0) {
                int row = rg * 64 + mi * 16 + lk * 4 + j;
                lds_s[cg * 128 + row] = sm;
                lds_q[cg * 128 + row] = q;
            }
        }
    }
    __syncthreads();
    if (t < 128) {
        float sm = lds_s[t] + lds_s[128 + t] + lds_s[256 + t] + lds_s[384 + t];
        float q  = lds_q[t] + lds_q[128 + t] + lds_q[256 + t] + lds_q[384 + t];
        float mu  = sm * (1.f / (float)EDIM);
        float var = q * (1.f / (float)EDIM) - mu * mu;
        lds_mu[t] = mu;
        lds_rs[t] = rsqrtf(var + 1e-6f);
    }
    __syncthreads();

    float gv[8], bv[8];
#pragma unroll
    for (int ni = 0; ni < 8; ++ni) {
        int col = cg * 128 + ni * 16 + lr;
        gv[ni] = gamma[col];
        bv[ni] = beta[col];
    }

#pragma unroll
    for (int mi = 0; mi < 4; ++mi) {
#pragma unroll
        for (int j = 0; j < 4; ++j) {
            int row = rg * 64 + mi * 16 + lk * 4 + j;
            int gr = m0 + row;
            if (gr < NROWS) {
                float mu = lds_mu[row], rs = lds_rs[row];
                float* op = out + (size_t)gr * EDIM + cg * 128 + lr;
#pragma unroll
                for (int ni = 0; ni < 8; ++ni)
                    op[ni * 16] = (acc[mi][ni][j] - mu) * rs * gv[ni] + bv[ni];
            }
        }
    }
}

// ---------------------------------------------------------------------------
extern "C" void kernel_launch(void* const* d_in, const int* in_sizes, int n_in,
                              void* d_out, int out_size, void* d_ws, size_t ws_size,
                              hipStream_t stream) {
    const float* node  = (const float*)d_in[0];   // [N, E]
    const float* obs   = (const float*)d_in[1];   // [M, O]
    const float* Wq    = (const float*)d_in[2];   // [E, E]
    const float* Wk    = (const float*)d_in[3];   // [E, O]
    const float* Wv    = (const float*)d_in[4];   // [E, O]
    const float* gamma = (const float*)d_in[5];   // [E]
    const float* beta  = (const float*)d_in[6];   // [E]
    float* out = (float*)d_out;

    float* ws = (float*)d_ws;
    float*          G  = ws;                        // [256,256] f32
    float*          P  = G  + ODIM * ODIM;          // [512,256] f32 (Wq^T Wk)
    float*          PG = P  + EDIM * ODIM;          // [512,256] f32
    unsigned short* Uf = (unsigned short*)(PG + EDIM * ODIM); // kk-major frag bf16

    // zero split-K accumulators G, P, PG
    hipMemsetAsync((void*)G, 0,
                   (ODIM * ODIM + 2 * EDIM * ODIM) * sizeof(float), stream);

    // D1: G = obs^T obs (split-K 16) + P = Wq^T Wk (split-K 4)
    gp_fused<<<dim3(384), 256, 0, stream>>>(obs, Wq, Wk, G, P);
    // D2: PG = P @ G              [512,256] K=256, split-K 2
    sgemm4<0, 0, 2, 0><<<dim3(4, 8, 2), 256, 0, stream>>>(P, G, PG, ODIM, ODIM, ODIM, ODIM);
    // D3: Uf = frag(PG @ Wv^T + I) [512,512] K=256, kk-major frag bf16
    sgemm4<0, 1, 1, 1><<<dim3(8, 8, 1), 256, 0, stream>>>(PG, Wv, Uf, EDIM, ODIM, ODIM, ODIM);
    // D4: out = LN(node @ (U+I)), 3-deep counted-vmcnt pipeline
    gemm_pipe_ln<<<dim3(NT2), 512, 0, stream>>>(node, Uf, gamma, beta, out);
}